// Round 9
// baseline (77.804 us; speedup 1.0000x reference)
//
#include <hip/hip_runtime.h>

typedef _Float16 h2 __attribute__((ext_vector_type(2)));

#define N_EDGES 4000000
#define N_NODES 100000
#define HID 8
#define NPT 4
#define NBLOCKS 1024
#define NTHREADS (NBLOCKS * 256)   // 262144 threads
#define NITER 4                    // 262144*4*4 = 4,194,304 slots >= N_EDGES
#define TWO_LOG2E 2.8853900817779268f
#define LN_EPS 1e-5f

// ws float-slot layout
#define O_GC0 0
#define O_BC0 8
#define O_GC1 16
#define O_BC1 24
#define O_GC2 32
#define O_BC2 40
#define O_B1  48
#define O_B2  56
#define O_B3  64    // 1 float
#define O_W1P 72    // 32 uint slots: packed h2 pairs, [j*4+q]
#define O_W2P 104   // 32
#define O_W3P 136   // 4
#define O_W0P 144   // 32 uint slots: per j, pairs {(w0,w1),(w2,0),(w3,w4),(w5,0)}
#define O_B0C 176   // 8 floats
#define O_XH  256   // N_NODES uint2 (8 B/node packed f16 features)
#define WS_FLOATS_NEEDED (256 + 2 * N_NODES)

#if __has_builtin(__builtin_amdgcn_fdot2)
#define FDOT2(a, b, c) __builtin_amdgcn_fdot2((a), (b), (c), false)
#else
#define FDOT2(a, b, c) ((float)(a)[0] * (float)(b)[0] + ((float)(a)[1] * (float)(b)[1] + (c)))
#endif

// fold tanh affine into W (W' = -2*(W - rowmean)), refine rows in f16, pack;
// b' = b + colsum(W), centered over j.
__device__ void prep_hidden_layer(const float* __restrict__ W,
                                  const float* __restrict__ b,
                                  float* __restrict__ ws, uint* __restrict__ wsu,
                                  int wofs, int bofs) {
    float Wc[64];
    for (int k = 0; k < 8; ++k) {
        float rm = 0.f;
        for (int j = 0; j < 8; ++j) rm += W[k * 8 + j];
        rm *= 0.125f;
        for (int j = 0; j < 8; ++j) Wc[k * 8 + j] = -2.f * (W[k * 8 + j] - rm);
    }
    for (int k = 0; k < 8; ++k) {  // refine: f16-rounded rows keep ~zero mean
        float m = 0.f;
        for (int j = 0; j < 8; ++j) m += (float)(_Float16)Wc[k * 8 + j];
        m *= 0.125f;
        for (int j = 0; j < 8; ++j) Wc[k * 8 + j] -= m;
    }
    for (int j = 0; j < 8; ++j)
        for (int q = 0; q < 4; ++q) {
            h2 v;
            v[0] = (_Float16)Wc[(2 * q) * 8 + j];
            v[1] = (_Float16)Wc[(2 * q + 1) * 8 + j];
            wsu[wofs + j * 4 + q] = __builtin_bit_cast(uint, v);
        }
    float mb = 0.f, tot = 0.f;
    for (int j = 0; j < 8; ++j) mb += b[j];
    for (int i = 0; i < 64; ++i) tot += W[i];
    for (int j = 0; j < 8; ++j) {
        float cs = 0.f;
        for (int k = 0; k < 8; ++k) cs += W[k * 8 + j];
        ws[bofs + j] = b[j] + cs - mb * 0.125f - tot * 0.125f;
    }
}

__global__ void prep_kernel(
    const float* __restrict__ x,
    const float* __restrict__ W0, const float* __restrict__ b0,
    const float* __restrict__ g0, const float* __restrict__ be0,
    const float* __restrict__ W1, const float* __restrict__ b1,
    const float* __restrict__ g1, const float* __restrict__ be1,
    const float* __restrict__ W2, const float* __restrict__ b2,
    const float* __restrict__ g2, const float* __restrict__ be2,
    const float* __restrict__ W3, const float* __restrict__ b3,
    float* __restrict__ ws, int use_tables)
{
    const int t = threadIdx.x;
    uint* wsu = reinterpret_cast<uint*>(ws);

    if (blockIdx.x == 0) {
        if (t == 0) {
            for (int j = 0; j < 8; ++j) {
                ws[O_GC0 + j] = g0[j] * TWO_LOG2E;  ws[O_BC0 + j] = be0[j] * TWO_LOG2E;
                ws[O_GC1 + j] = g1[j] * TWO_LOG2E;  ws[O_BC1 + j] = be1[j] * TWO_LOG2E;
                ws[O_GC2 + j] = g2[j] * TWO_LOG2E;  ws[O_BC2 + j] = be2[j] * TWO_LOG2E;
            }
        } else if (t == 1) {
            // W0: center rows over j, refine in f16, pack dot2 pairs; center b0
            float Wc[48];
            for (int k = 0; k < 6; ++k) {
                float rm = 0.f;
                for (int j = 0; j < 8; ++j) rm += W0[k * 8 + j];
                rm *= 0.125f;
                for (int j = 0; j < 8; ++j) Wc[k * 8 + j] = W0[k * 8 + j] - rm;
            }
            for (int k = 0; k < 6; ++k) {
                float m = 0.f;
                for (int j = 0; j < 8; ++j) m += (float)(_Float16)Wc[k * 8 + j];
                m *= 0.125f;
                for (int j = 0; j < 8; ++j) Wc[k * 8 + j] -= m;
            }
            for (int j = 0; j < 8; ++j) {
                h2 v;
                v[0] = (_Float16)Wc[0 * 8 + j]; v[1] = (_Float16)Wc[1 * 8 + j];
                wsu[O_W0P + j * 4 + 0] = __builtin_bit_cast(uint, v);
                v[0] = (_Float16)Wc[2 * 8 + j]; v[1] = (_Float16)0.f;
                wsu[O_W0P + j * 4 + 1] = __builtin_bit_cast(uint, v);
                v[0] = (_Float16)Wc[3 * 8 + j]; v[1] = (_Float16)Wc[4 * 8 + j];
                wsu[O_W0P + j * 4 + 2] = __builtin_bit_cast(uint, v);
                v[0] = (_Float16)Wc[5 * 8 + j]; v[1] = (_Float16)0.f;
                wsu[O_W0P + j * 4 + 3] = __builtin_bit_cast(uint, v);
            }
            float bm = 0.f;
            for (int j = 0; j < 8; ++j) bm += b0[j];
            bm *= 0.125f;
            for (int j = 0; j < 8; ++j) ws[O_B0C + j] = b0[j] - bm;
        } else if (t == 2) {
            prep_hidden_layer(W1, b1, ws, wsu, O_W1P, O_B1);
        } else if (t == 3) {
            prep_hidden_layer(W2, b2, ws, wsu, O_W2P, O_B2);
        } else if (t == 4) {
            float s = 0.f;
            for (int k = 0; k < 8; ++k) s += W3[k];
            ws[O_B3] = b3[0] + s;
            for (int q = 0; q < 4; ++q) {
                h2 v;
                v[0] = (_Float16)(-2.f * W3[2 * q]);
                v[1] = (_Float16)(-2.f * W3[2 * q + 1]);
                wsu[O_W3P + q] = __builtin_bit_cast(uint, v);
            }
        }
    }

    if (use_tables) {
        const int n = blockIdx.x * blockDim.x + t;
        if (n < N_NODES) {
            const float x0 = x[n * 3 + 0], x1 = x[n * 3 + 1], x2 = x[n * 3 + 2];
            uint2 v;
            v.x = __builtin_bit_cast(uint, __builtin_amdgcn_cvt_pkrtz(x0, x1));
            v.y = __builtin_bit_cast(uint, __builtin_amdgcn_cvt_pkrtz(x2, 0.f));
            reinterpret_cast<uint2*>(ws + O_XH)[n] = v;
        }
    }
}

// Mean-free LN + folded-tanh sigmoid u = 1/(1+exp2(y)); pair-rcp; packed f16 out.
template<int N>
__device__ __forceinline__ void ln_pack(const float (&z)[N][HID],
                                        const float* __restrict__ gc,
                                        const float* __restrict__ bc,
                                        h2 (&p)[N][4]) {
    float r[N];
#pragma unroll
    for (int e = 0; e < N; ++e) {
        float va = 0.f;
#pragma unroll
        for (int j = 0; j < HID; ++j) va = __builtin_fmaf(z[e][j], z[e][j], va);
        r[e] = __builtin_amdgcn_rsqf(__builtin_fmaf(va, 0.125f, LN_EPS));
    }
    float e1[N][HID];
#pragma unroll
    for (int j = 0; j < HID; ++j) {
        const float gcj = gc[j], bcj = bc[j];
#pragma unroll
        for (int e = 0; e < N; ++e) {
            const float y = __builtin_fmaf(z[e][j], r[e] * gcj, bcj);
            e1[e][j] = __builtin_amdgcn_exp2f(y) + 1.0f;
        }
    }
#pragma unroll
    for (int q = 0; q < 4; ++q)
#pragma unroll
        for (int e = 0; e < N; ++e) {
            const float a = e1[e][2 * q], b = e1[e][2 * q + 1];
            const float pr = __builtin_amdgcn_rcpf(a * b);
            p[e][q] = __builtin_bit_cast(h2,
                __builtin_amdgcn_cvt_pkrtz(b * pr, a * pr));
        }
}

template<int N>
__device__ __forceinline__ void lin8_dot(const h2 (&p)[N][4],
                                         const uint* __restrict__ wp,
                                         const float* __restrict__ b,
                                         float (&zo)[N][HID]) {
#pragma unroll
    for (int j = 0; j < HID; ++j) {
        const float bj = b[j];
        const h2 w0 = __builtin_bit_cast(h2, wp[j * 4 + 0]);
        const h2 w1 = __builtin_bit_cast(h2, wp[j * 4 + 1]);
        const h2 w2 = __builtin_bit_cast(h2, wp[j * 4 + 2]);
        const h2 w3 = __builtin_bit_cast(h2, wp[j * 4 + 3]);
#pragma unroll
        for (int e = 0; e < N; ++e) {
            float acc = FDOT2(p[e][0], w0, bj);
            acc = FDOT2(p[e][1], w1, acc);
            acc = FDOT2(p[e][2], w2, acc);
            zo[e][j] = FDOT2(p[e][3], w3, acc);
        }
    }
}

// full per-4-edge MLP from packed f16 endpoint features; store guarded
__device__ __forceinline__ void compute_store(
    const h2 (&s01)[NPT], const h2 (&s2z)[NPT],
    const h2 (&d01)[NPT], const h2 (&d2z)[NPT],
    const float* __restrict__ ws, const uint* __restrict__ wsu,
    float* __restrict__ out, uint b)
{
    float z[NPT][HID];
#pragma unroll
    for (int j = 0; j < HID; ++j) {
        const h2 wj0 = __builtin_bit_cast(h2, wsu[O_W0P + j * 4 + 0]);
        const h2 wj1 = __builtin_bit_cast(h2, wsu[O_W0P + j * 4 + 1]);
        const h2 wj2 = __builtin_bit_cast(h2, wsu[O_W0P + j * 4 + 2]);
        const h2 wj3 = __builtin_bit_cast(h2, wsu[O_W0P + j * 4 + 3]);
        const float bb = ws[O_B0C + j];
#pragma unroll
        for (int e = 0; e < NPT; ++e) {
            float a = FDOT2(s01[e], wj0, bb);
            a = FDOT2(s2z[e], wj1, a);
            a = FDOT2(d01[e], wj2, a);
            z[e][j] = FDOT2(d2z[e], wj3, a);
        }
    }

    h2 p[NPT][4];
    ln_pack<NPT>(z, ws + O_GC0, ws + O_BC0, p);
    lin8_dot<NPT>(p, wsu + O_W1P, ws + O_B1, z);
    ln_pack<NPT>(z, ws + O_GC1, ws + O_BC1, p);
    lin8_dot<NPT>(p, wsu + O_W2P, ws + O_B2, z);
    ln_pack<NPT>(z, ws + O_GC2, ws + O_BC2, p);

    const h2 w30 = __builtin_bit_cast(h2, wsu[O_W3P + 0]);
    const h2 w31 = __builtin_bit_cast(h2, wsu[O_W3P + 1]);
    const h2 w32 = __builtin_bit_cast(h2, wsu[O_W3P + 2]);
    const h2 w33 = __builtin_bit_cast(h2, wsu[O_W3P + 3]);
    const float bb3 = ws[O_B3];
    float o[NPT];
#pragma unroll
    for (int e = 0; e < NPT; ++e) {
        float acc = FDOT2(p[e][0], w30, bb3);
        acc = FDOT2(p[e][1], w31, acc);
        acc = FDOT2(p[e][2], w32, acc);
        o[e] = FDOT2(p[e][3], w33, acc);
    }
    if (b < N_EDGES)
        *reinterpret_cast<float4*>(out + b) = make_float4(o[0], o[1], o[2], o[3]);
}

__device__ __forceinline__ void gath(uint2 (&gs)[NPT], uint2 (&gd)[NPT],
                                     const int4& s, const int4& d,
                                     const uint2* __restrict__ XH) {
    gs[0] = XH[(uint)s.x]; gs[1] = XH[(uint)s.y];
    gs[2] = XH[(uint)s.z]; gs[3] = XH[(uint)s.w];
    gd[0] = XH[(uint)d.x]; gd[1] = XH[(uint)d.y];
    gd[2] = XH[(uint)d.z]; gd[3] = XH[(uint)d.w];
}

__device__ __forceinline__ void unpack(const uint2 (&gs)[NPT], const uint2 (&gd)[NPT],
                                       h2 (&s01)[NPT], h2 (&s2z)[NPT],
                                       h2 (&d01)[NPT], h2 (&d2z)[NPT]) {
#pragma unroll
    for (int e = 0; e < NPT; ++e) {
        s01[e] = __builtin_bit_cast(h2, gs[e].x);
        s2z[e] = __builtin_bit_cast(h2, gs[e].y);
        d01[e] = __builtin_bit_cast(h2, gd[e].x);
        d2z[e] = __builtin_bit_cast(h2, gd[e].y);
    }
}

template<bool UT>
__global__ __launch_bounds__(256) void edge_mlp_kernel(
    const float* __restrict__ x,
    const int*   __restrict__ ei,
    const float* __restrict__ ws,
    float* __restrict__ out)
{
    const uint tid = blockIdx.x * 256u + threadIdx.x;
    const uint* wsu = reinterpret_cast<const uint*>(ws);

    if (!UT) {
        // fallback: no table, simple loop with scalar x loads
        for (int it = 0; it < NITER; ++it) {
            const uint b = ((uint)it * NTHREADS + tid) * 4u;
            if (b >= N_EDGES) return;
            const int4 sv = *reinterpret_cast<const int4*>(ei + b);
            const int4 dv = *reinterpret_cast<const int4*>(ei + N_EDGES + b);
            const uint si[NPT] = {(uint)sv.x, (uint)sv.y, (uint)sv.z, (uint)sv.w};
            const uint di[NPT] = {(uint)dv.x, (uint)dv.y, (uint)dv.z, (uint)dv.w};
            h2 s01[NPT], s2z[NPT], d01[NPT], d2z[NPT];
#pragma unroll
            for (int e = 0; e < NPT; ++e) {
                const float s0 = x[si[e] * 3u], s1 = x[si[e] * 3u + 1], s2 = x[si[e] * 3u + 2];
                const float d0 = x[di[e] * 3u], d1 = x[di[e] * 3u + 1], d2 = x[di[e] * 3u + 2];
                s01[e] = __builtin_bit_cast(h2, __builtin_amdgcn_cvt_pkrtz(s0, s1));
                s2z[e] = __builtin_bit_cast(h2, __builtin_amdgcn_cvt_pkrtz(s2, 0.f));
                d01[e] = __builtin_bit_cast(h2, __builtin_amdgcn_cvt_pkrtz(d0, d1));
                d2z[e] = __builtin_bit_cast(h2, __builtin_amdgcn_cvt_pkrtz(d2, 0.f));
            }
            compute_store(s01, s2z, d01, d2z, ws, wsu, out, b);
        }
        return;
    }

    const uint2* XH = reinterpret_cast<const uint2*>(ws + O_XH);

    // chunk base for iteration it (only it=3 can exceed; clamp loads, guard store)
    const uint b0 = tid * 4u;
    const uint b1 = (1u * NTHREADS + tid) * 4u;
    const uint b2 = (2u * NTHREADS + tid) * 4u;
    const uint b3 = (3u * NTHREADS + tid) * 4u;
    const uint b3c = b3 < N_EDGES ? b3 : (N_EDGES - 4u);

    // ---- static 2-deep software pipeline ----
    // idx loads it0, it1
    int4 s0 = *reinterpret_cast<const int4*>(ei + b0);
    int4 d0 = *reinterpret_cast<const int4*>(ei + N_EDGES + b0);
    int4 s1 = *reinterpret_cast<const int4*>(ei + b1);
    int4 d1 = *reinterpret_cast<const int4*>(ei + N_EDGES + b1);
    // gathers it0; idx it2
    uint2 gs0[NPT], gd0[NPT];
    gath(gs0, gd0, s0, d0, XH);
    int4 s2 = *reinterpret_cast<const int4*>(ei + b2);
    int4 d2 = *reinterpret_cast<const int4*>(ei + N_EDGES + b2);
    // gathers it1; idx it3
    uint2 gs1[NPT], gd1[NPT];
    gath(gs1, gd1, s1, d1, XH);
    int4 s3 = *reinterpret_cast<const int4*>(ei + b3c);
    int4 d3 = *reinterpret_cast<const int4*>(ei + N_EDGES + b3c);

    h2 s01[NPT], s2z[NPT], d01[NPT], d2z[NPT];

    // it0 compute; issue gathers it2
    uint2 gs2[NPT], gd2[NPT];
    gath(gs2, gd2, s2, d2, XH);
    unpack(gs0, gd0, s01, s2z, d01, d2z);
    compute_store(s01, s2z, d01, d2z, ws, wsu, out, b0);

    // it1 compute; issue gathers it3
    uint2 gs3[NPT], gd3[NPT];
    gath(gs3, gd3, s3, d3, XH);
    unpack(gs1, gd1, s01, s2z, d01, d2z);
    compute_store(s01, s2z, d01, d2z, ws, wsu, out, b1);

    // it2 compute
    unpack(gs2, gd2, s01, s2z, d01, d2z);
    compute_store(s01, s2z, d01, d2z, ws, wsu, out, b2);

    // it3 compute (store guarded by b3)
    unpack(gs3, gd3, s01, s2z, d01, d2z);
    compute_store(s01, s2z, d01, d2z, ws, wsu, out, b3);
}

extern "C" void kernel_launch(void* const* d_in, const int* in_sizes, int n_in,
                              void* d_out, int out_size, void* d_ws, size_t ws_size,
                              hipStream_t stream) {
    const float* x   = (const float*)d_in[0];
    const int*   ei  = (const int*)d_in[1];
    const float* W0  = (const float*)d_in[2];
    const float* b0  = (const float*)d_in[3];
    const float* g0  = (const float*)d_in[4];
    const float* be0 = (const float*)d_in[5];
    const float* W1  = (const float*)d_in[6];
    const float* b1  = (const float*)d_in[7];
    const float* g1  = (const float*)d_in[8];
    const float* be1 = (const float*)d_in[9];
    const float* W2  = (const float*)d_in[10];
    const float* b2  = (const float*)d_in[11];
    const float* g2  = (const float*)d_in[12];
    const float* be2 = (const float*)d_in[13];
    const float* W3  = (const float*)d_in[14];
    const float* b3  = (const float*)d_in[15];
    float* out = (float*)d_out;
    float* ws  = (float*)d_ws;

    const bool ut = ws_size >= (size_t)WS_FLOATS_NEEDED * sizeof(float);
    const int prep_blocks = ut ? (N_NODES + 255) / 256 : 1;
    prep_kernel<<<prep_blocks, 256, 0, stream>>>(
        x, W0, b0, g0, be0, W1, b1, g1, be1, W2, b2, g2, be2, W3, b3,
        ws, ut ? 1 : 0);

    if (ut)
        edge_mlp_kernel<true><<<NBLOCKS, 256, 0, stream>>>(x, ei, ws, out);
    else
        edge_mlp_kernel<false><<<NBLOCKS, 256, 0, stream>>>(x, ei, ws, out);
}

// Round 10
// 62.644 us; speedup vs baseline: 1.2420x; 1.2420x over previous
//
#include <hip/hip_runtime.h>

typedef _Float16 h2 __attribute__((ext_vector_type(2)));
typedef float f4v __attribute__((ext_vector_type(4)));
typedef f4v f4u __attribute__((aligned(4)));   // 4B-aligned float4 (unaligned dwordx4)

#define N_EDGES 4000000
#define HID 8
#define NPT 4
#define TWO_LOG2E 2.8853900817779268f
#define LN_EPS 1e-5f

// ws float-slot layout (weights only)
#define O_GC0 0
#define O_BC0 8
#define O_GC1 16
#define O_BC1 24
#define O_GC2 32
#define O_BC2 40
#define O_B1  48
#define O_B2  56
#define O_B3  64    // 1 float
#define O_W1P 72    // 32 uint slots: packed h2 pairs, [j*4+q]
#define O_W2P 104   // 32
#define O_W3P 136   // 4
#define O_W0P 144   // 32 uint slots: per j, pairs {(w0,w1),(w2,0),(w3,w4),(w5,0)}
#define O_B0C 176   // 8 floats

#if __has_builtin(__builtin_amdgcn_fdot2)
#define FDOT2(a, b, c) __builtin_amdgcn_fdot2((a), (b), (c), false)
#else
#define FDOT2(a, b, c) ((float)(a)[0] * (float)(b)[0] + ((float)(a)[1] * (float)(b)[1] + (c)))
#endif

// fold tanh affine into W (W' = -2*(W - rowmean)), refine rows in f16, pack;
// b' = b + colsum(W), centered over j.
__device__ void prep_hidden_layer(const float* __restrict__ W,
                                  const float* __restrict__ b,
                                  float* __restrict__ ws, uint* __restrict__ wsu,
                                  int wofs, int bofs) {
    float Wc[64];
    for (int k = 0; k < 8; ++k) {
        float rm = 0.f;
        for (int j = 0; j < 8; ++j) rm += W[k * 8 + j];
        rm *= 0.125f;
        for (int j = 0; j < 8; ++j) Wc[k * 8 + j] = -2.f * (W[k * 8 + j] - rm);
    }
    for (int k = 0; k < 8; ++k) {  // refine: f16-rounded rows keep ~zero mean
        float m = 0.f;
        for (int j = 0; j < 8; ++j) m += (float)(_Float16)Wc[k * 8 + j];
        m *= 0.125f;
        for (int j = 0; j < 8; ++j) Wc[k * 8 + j] -= m;
    }
    for (int j = 0; j < 8; ++j)
        for (int q = 0; q < 4; ++q) {
            h2 v;
            v[0] = (_Float16)Wc[(2 * q) * 8 + j];
            v[1] = (_Float16)Wc[(2 * q + 1) * 8 + j];
            wsu[wofs + j * 4 + q] = __builtin_bit_cast(uint, v);
        }
    float mb = 0.f, tot = 0.f;
    for (int j = 0; j < 8; ++j) mb += b[j];
    for (int i = 0; i < 64; ++i) tot += W[i];
    for (int j = 0; j < 8; ++j) {
        float cs = 0.f;
        for (int k = 0; k < 8; ++k) cs += W[k * 8 + j];
        ws[bofs + j] = b[j] + cs - mb * 0.125f - tot * 0.125f;
    }
}

__global__ void prep_kernel(
    const float* __restrict__ W0, const float* __restrict__ b0,
    const float* __restrict__ g0, const float* __restrict__ be0,
    const float* __restrict__ W1, const float* __restrict__ b1,
    const float* __restrict__ g1, const float* __restrict__ be1,
    const float* __restrict__ W2, const float* __restrict__ b2,
    const float* __restrict__ g2, const float* __restrict__ be2,
    const float* __restrict__ W3, const float* __restrict__ b3,
    float* __restrict__ ws)
{
    const int t = threadIdx.x;
    uint* wsu = reinterpret_cast<uint*>(ws);

    if (t == 0) {
        for (int j = 0; j < 8; ++j) {
            ws[O_GC0 + j] = g0[j] * TWO_LOG2E;  ws[O_BC0 + j] = be0[j] * TWO_LOG2E;
            ws[O_GC1 + j] = g1[j] * TWO_LOG2E;  ws[O_BC1 + j] = be1[j] * TWO_LOG2E;
            ws[O_GC2 + j] = g2[j] * TWO_LOG2E;  ws[O_BC2 + j] = be2[j] * TWO_LOG2E;
        }
    } else if (t == 1) {
        // W0: center rows over j, refine in f16, pack dot2 pairs; center b0
        float Wc[48];
        for (int k = 0; k < 6; ++k) {
            float rm = 0.f;
            for (int j = 0; j < 8; ++j) rm += W0[k * 8 + j];
            rm *= 0.125f;
            for (int j = 0; j < 8; ++j) Wc[k * 8 + j] = W0[k * 8 + j] - rm;
        }
        for (int k = 0; k < 6; ++k) {
            float m = 0.f;
            for (int j = 0; j < 8; ++j) m += (float)(_Float16)Wc[k * 8 + j];
            m *= 0.125f;
            for (int j = 0; j < 8; ++j) Wc[k * 8 + j] -= m;
        }
        for (int j = 0; j < 8; ++j) {
            h2 v;
            v[0] = (_Float16)Wc[0 * 8 + j]; v[1] = (_Float16)Wc[1 * 8 + j];
            wsu[O_W0P + j * 4 + 0] = __builtin_bit_cast(uint, v);
            v[0] = (_Float16)Wc[2 * 8 + j]; v[1] = (_Float16)0.f;
            wsu[O_W0P + j * 4 + 1] = __builtin_bit_cast(uint, v);
            v[0] = (_Float16)Wc[3 * 8 + j]; v[1] = (_Float16)Wc[4 * 8 + j];
            wsu[O_W0P + j * 4 + 2] = __builtin_bit_cast(uint, v);
            v[0] = (_Float16)Wc[5 * 8 + j]; v[1] = (_Float16)0.f;
            wsu[O_W0P + j * 4 + 3] = __builtin_bit_cast(uint, v);
        }
        float bm = 0.f;
        for (int j = 0; j < 8; ++j) bm += b0[j];
        bm *= 0.125f;
        for (int j = 0; j < 8; ++j) ws[O_B0C + j] = b0[j] - bm;
    } else if (t == 2) {
        prep_hidden_layer(W1, b1, ws, wsu, O_W1P, O_B1);
    } else if (t == 3) {
        prep_hidden_layer(W2, b2, ws, wsu, O_W2P, O_B2);
    } else if (t == 4) {
        float s = 0.f;
        for (int k = 0; k < 8; ++k) s += W3[k];
        ws[O_B3] = b3[0] + s;
        for (int q = 0; q < 4; ++q) {
            h2 v;
            v[0] = (_Float16)(-2.f * W3[2 * q]);
            v[1] = (_Float16)(-2.f * W3[2 * q + 1]);
            wsu[O_W3P + q] = __builtin_bit_cast(uint, v);
        }
    }
}

// Mean-free LN + folded-tanh sigmoid u = 1/(1+exp2(y)); pair-rcp; packed f16 out.
template<int N>
__device__ __forceinline__ void ln_pack(const float (&z)[N][HID],
                                        const float* __restrict__ gc,
                                        const float* __restrict__ bc,
                                        h2 (&p)[N][4]) {
    float r[N];
#pragma unroll
    for (int e = 0; e < N; ++e) {
        float va = 0.f;
#pragma unroll
        for (int j = 0; j < HID; ++j) va = __builtin_fmaf(z[e][j], z[e][j], va);
        r[e] = __builtin_amdgcn_rsqf(__builtin_fmaf(va, 0.125f, LN_EPS));
    }
    float e1[N][HID];
#pragma unroll
    for (int j = 0; j < HID; ++j) {
        const float gcj = gc[j], bcj = bc[j];
#pragma unroll
        for (int e = 0; e < N; ++e) {
            const float y = __builtin_fmaf(z[e][j], r[e] * gcj, bcj);
            e1[e][j] = __builtin_amdgcn_exp2f(y) + 1.0f;
        }
    }
#pragma unroll
    for (int q = 0; q < 4; ++q)
#pragma unroll
        for (int e = 0; e < N; ++e) {
            const float a = e1[e][2 * q], b = e1[e][2 * q + 1];
            const float pr = __builtin_amdgcn_rcpf(a * b);
            p[e][q] = __builtin_bit_cast(h2,
                __builtin_amdgcn_cvt_pkrtz(b * pr, a * pr));
        }
}

template<int N>
__device__ __forceinline__ void lin8_dot(const h2 (&p)[N][4],
                                         const uint* __restrict__ wp,
                                         const float* __restrict__ b,
                                         float (&zo)[N][HID]) {
#pragma unroll
    for (int j = 0; j < HID; ++j) {
        const float bj = b[j];
        const h2 w0 = __builtin_bit_cast(h2, wp[j * 4 + 0]);
        const h2 w1 = __builtin_bit_cast(h2, wp[j * 4 + 1]);
        const h2 w2 = __builtin_bit_cast(h2, wp[j * 4 + 2]);
        const h2 w3 = __builtin_bit_cast(h2, wp[j * 4 + 3]);
#pragma unroll
        for (int e = 0; e < N; ++e) {
            float acc = FDOT2(p[e][0], w0, bj);
            acc = FDOT2(p[e][1], w1, acc);
            acc = FDOT2(p[e][2], w2, acc);
            zo[e][j] = FDOT2(p[e][3], w3, acc);
        }
    }
}

// full MLP for a PAIR of edges from raw f32 endpoint vectors
__device__ __forceinline__ void mlp2(const f4u& vsa, const f4u& vsb,
                                     const f4u& vda, const f4u& vdb,
                                     const float* __restrict__ ws,
                                     const uint* __restrict__ wsu,
                                     float& oa, float& ob)
{
    h2 s01[2], s2z[2], d01[2], d2z[2];
    s01[0] = __builtin_bit_cast(h2, __builtin_amdgcn_cvt_pkrtz(vsa[0], vsa[1]));
    s2z[0] = __builtin_bit_cast(h2, __builtin_amdgcn_cvt_pkrtz(vsa[2], 0.f));
    d01[0] = __builtin_bit_cast(h2, __builtin_amdgcn_cvt_pkrtz(vda[0], vda[1]));
    d2z[0] = __builtin_bit_cast(h2, __builtin_amdgcn_cvt_pkrtz(vda[2], 0.f));
    s01[1] = __builtin_bit_cast(h2, __builtin_amdgcn_cvt_pkrtz(vsb[0], vsb[1]));
    s2z[1] = __builtin_bit_cast(h2, __builtin_amdgcn_cvt_pkrtz(vsb[2], 0.f));
    d01[1] = __builtin_bit_cast(h2, __builtin_amdgcn_cvt_pkrtz(vdb[0], vdb[1]));
    d2z[1] = __builtin_bit_cast(h2, __builtin_amdgcn_cvt_pkrtz(vdb[2], 0.f));

    float z[2][HID];
#pragma unroll
    for (int j = 0; j < HID; ++j) {
        const h2 wj0 = __builtin_bit_cast(h2, wsu[O_W0P + j * 4 + 0]);
        const h2 wj1 = __builtin_bit_cast(h2, wsu[O_W0P + j * 4 + 1]);
        const h2 wj2 = __builtin_bit_cast(h2, wsu[O_W0P + j * 4 + 2]);
        const h2 wj3 = __builtin_bit_cast(h2, wsu[O_W0P + j * 4 + 3]);
        const float bb = ws[O_B0C + j];
#pragma unroll
        for (int e = 0; e < 2; ++e) {
            float a = FDOT2(s01[e], wj0, bb);
            a = FDOT2(s2z[e], wj1, a);
            a = FDOT2(d01[e], wj2, a);
            z[e][j] = FDOT2(d2z[e], wj3, a);
        }
    }

    h2 p[2][4];
    ln_pack<2>(z, ws + O_GC0, ws + O_BC0, p);
    lin8_dot<2>(p, wsu + O_W1P, ws + O_B1, z);
    ln_pack<2>(z, ws + O_GC1, ws + O_BC1, p);
    lin8_dot<2>(p, wsu + O_W2P, ws + O_B2, z);
    ln_pack<2>(z, ws + O_GC2, ws + O_BC2, p);

    const h2 w30 = __builtin_bit_cast(h2, wsu[O_W3P + 0]);
    const h2 w31 = __builtin_bit_cast(h2, wsu[O_W3P + 1]);
    const h2 w32 = __builtin_bit_cast(h2, wsu[O_W3P + 2]);
    const h2 w33 = __builtin_bit_cast(h2, wsu[O_W3P + 3]);
    const float bb3 = ws[O_B3];
    {
        float acc = FDOT2(p[0][0], w30, bb3);
        acc = FDOT2(p[0][1], w31, acc);
        acc = FDOT2(p[0][2], w32, acc);
        oa = FDOT2(p[0][3], w33, acc);
    }
    {
        float acc = FDOT2(p[1][0], w30, bb3);
        acc = FDOT2(p[1][1], w31, acc);
        acc = FDOT2(p[1][2], w32, acc);
        ob = FDOT2(p[1][3], w33, acc);
    }
}

__global__ __launch_bounds__(256) void edge_mlp_kernel(
    const float* __restrict__ x,
    const int*   __restrict__ ei,
    const float* __restrict__ ws,
    float* __restrict__ out)
{
    const int t = blockIdx.x * blockDim.x + threadIdx.x;
    const int base = t * NPT;
    if (base >= N_EDGES) return;

    const uint* wsu = reinterpret_cast<const uint*>(ws);
    const int4 sv = *reinterpret_cast<const int4*>(ei + base);
    const int4 dv = *reinterpret_cast<const int4*>(ei + N_EDGES + base);

    // issue ALL 8 gathers up front (independent, stay in flight)
    const f4u vs0 = *reinterpret_cast<const f4u*>(x + (uint)sv.x * 3u);
    const f4u vs1 = *reinterpret_cast<const f4u*>(x + (uint)sv.y * 3u);
    const f4u vs2 = *reinterpret_cast<const f4u*>(x + (uint)sv.z * 3u);
    const f4u vs3 = *reinterpret_cast<const f4u*>(x + (uint)sv.w * 3u);
    const f4u vd0 = *reinterpret_cast<const f4u*>(x + (uint)dv.x * 3u);
    const f4u vd1 = *reinterpret_cast<const f4u*>(x + (uint)dv.y * 3u);
    const f4u vd2 = *reinterpret_cast<const f4u*>(x + (uint)dv.z * 3u);
    const f4u vd3 = *reinterpret_cast<const f4u*>(x + (uint)dv.w * 3u);

    float o0, o1, o2, o3;
    // group A: first use waits only on its own 4 gathers (vmcnt counted);
    // its ~1200cy of compute hides the remaining 4 loads' latency
    mlp2(vs0, vs1, vd0, vd1, ws, wsu, o0, o1);
    // group B
    mlp2(vs2, vs3, vd2, vd3, ws, wsu, o2, o3);

    *reinterpret_cast<float4*>(out + base) = make_float4(o0, o1, o2, o3);
}

extern "C" void kernel_launch(void* const* d_in, const int* in_sizes, int n_in,
                              void* d_out, int out_size, void* d_ws, size_t ws_size,
                              hipStream_t stream) {
    const float* x   = (const float*)d_in[0];
    const int*   ei  = (const int*)d_in[1];
    const float* W0  = (const float*)d_in[2];
    const float* b0  = (const float*)d_in[3];
    const float* g0  = (const float*)d_in[4];
    const float* be0 = (const float*)d_in[5];
    const float* W1  = (const float*)d_in[6];
    const float* b1  = (const float*)d_in[7];
    const float* g1  = (const float*)d_in[8];
    const float* be1 = (const float*)d_in[9];
    const float* W2  = (const float*)d_in[10];
    const float* b2  = (const float*)d_in[11];
    const float* g2  = (const float*)d_in[12];
    const float* be2 = (const float*)d_in[13];
    const float* W3  = (const float*)d_in[14];
    const float* b3  = (const float*)d_in[15];
    float* out = (float*)d_out;
    float* ws  = (float*)d_ws;

    prep_kernel<<<1, 64, 0, stream>>>(W0, b0, g0, be0, W1, b1, g1, be1,
                                      W2, b2, g2, be2, W3, b3, ws);

    const int nthreads = N_EDGES / NPT;          // 1,000,000
    const int blocks = (nthreads + 255) / 256;   // 3907
    edge_mlp_kernel<<<blocks, 256, 0, stream>>>(x, ei, ws, out);
}

// Round 11
// 54.942 us; speedup vs baseline: 1.4161x; 1.1402x over previous
//
#include <hip/hip_runtime.h>

typedef _Float16 h2 __attribute__((ext_vector_type(2)));
typedef float f4v __attribute__((ext_vector_type(4)));
typedef f4v f4u __attribute__((aligned(4)));   // 4B-aligned float4 (unaligned dwordx4)

#define N_EDGES 4000000
#define HID 8
#define TWO_LOG2E 2.8853900817779268f
#define LN_EPS 1e-5f

// ws float-slot layout (weights only)
#define O_GC0 0
#define O_BC0 8
#define O_GC1 16
#define O_BC1 24
#define O_GC2 32
#define O_BC2 40
#define O_B1  48
#define O_B2  56
#define O_B3  64    // 1 float
#define O_W1P 72    // 32 uint slots: packed h2 pairs, [j*4+q]
#define O_W2P 104   // 32
#define O_W3P 136   // 4
#define O_W0P 144   // 32 uint slots: per j, pairs {(w0,w1),(w2,0),(w3,w4),(w5,0)}
#define O_B0C 176   // 8 floats

#if __has_builtin(__builtin_amdgcn_fdot2)
#define FDOT2(a, b, c) __builtin_amdgcn_fdot2((a), (b), (c), false)
#else
#define FDOT2(a, b, c) ((float)(a)[0] * (float)(b)[0] + ((float)(a)[1] * (float)(b)[1] + (c)))
#endif

// fold tanh affine into W (W' = -2*(W - rowmean)), refine rows in f16, pack;
// b' = b + colsum(W), centered over j.
__device__ void prep_hidden_layer(const float* __restrict__ W,
                                  const float* __restrict__ b,
                                  float* __restrict__ ws, uint* __restrict__ wsu,
                                  int wofs, int bofs) {
    float Wc[64];
    for (int k = 0; k < 8; ++k) {
        float rm = 0.f;
        for (int j = 0; j < 8; ++j) rm += W[k * 8 + j];
        rm *= 0.125f;
        for (int j = 0; j < 8; ++j) Wc[k * 8 + j] = -2.f * (W[k * 8 + j] - rm);
    }
    for (int k = 0; k < 8; ++k) {  // refine: f16-rounded rows keep ~zero mean
        float m = 0.f;
        for (int j = 0; j < 8; ++j) m += (float)(_Float16)Wc[k * 8 + j];
        m *= 0.125f;
        for (int j = 0; j < 8; ++j) Wc[k * 8 + j] -= m;
    }
    for (int j = 0; j < 8; ++j)
        for (int q = 0; q < 4; ++q) {
            h2 v;
            v[0] = (_Float16)Wc[(2 * q) * 8 + j];
            v[1] = (_Float16)Wc[(2 * q + 1) * 8 + j];
            wsu[wofs + j * 4 + q] = __builtin_bit_cast(uint, v);
        }
    float mb = 0.f, tot = 0.f;
    for (int j = 0; j < 8; ++j) mb += b[j];
    for (int i = 0; i < 64; ++i) tot += W[i];
    for (int j = 0; j < 8; ++j) {
        float cs = 0.f;
        for (int k = 0; k < 8; ++k) cs += W[k * 8 + j];
        ws[bofs + j] = b[j] + cs - mb * 0.125f - tot * 0.125f;
    }
}

__global__ void prep_kernel(
    const float* __restrict__ W0, const float* __restrict__ b0,
    const float* __restrict__ g0, const float* __restrict__ be0,
    const float* __restrict__ W1, const float* __restrict__ b1,
    const float* __restrict__ g1, const float* __restrict__ be1,
    const float* __restrict__ W2, const float* __restrict__ b2,
    const float* __restrict__ g2, const float* __restrict__ be2,
    const float* __restrict__ W3, const float* __restrict__ b3,
    float* __restrict__ ws)
{
    const int t = threadIdx.x;
    uint* wsu = reinterpret_cast<uint*>(ws);

    if (t == 0) {
        for (int j = 0; j < 8; ++j) {
            ws[O_GC0 + j] = g0[j] * TWO_LOG2E;  ws[O_BC0 + j] = be0[j] * TWO_LOG2E;
            ws[O_GC1 + j] = g1[j] * TWO_LOG2E;  ws[O_BC1 + j] = be1[j] * TWO_LOG2E;
            ws[O_GC2 + j] = g2[j] * TWO_LOG2E;  ws[O_BC2 + j] = be2[j] * TWO_LOG2E;
        }
    } else if (t == 1) {
        // W0: center rows over j, refine in f16, pack dot2 pairs; center b0
        float Wc[48];
        for (int k = 0; k < 6; ++k) {
            float rm = 0.f;
            for (int j = 0; j < 8; ++j) rm += W0[k * 8 + j];
            rm *= 0.125f;
            for (int j = 0; j < 8; ++j) Wc[k * 8 + j] = W0[k * 8 + j] - rm;
        }
        for (int k = 0; k < 6; ++k) {
            float m = 0.f;
            for (int j = 0; j < 8; ++j) m += (float)(_Float16)Wc[k * 8 + j];
            m *= 0.125f;
            for (int j = 0; j < 8; ++j) Wc[k * 8 + j] -= m;
        }
        for (int j = 0; j < 8; ++j) {
            h2 v;
            v[0] = (_Float16)Wc[0 * 8 + j]; v[1] = (_Float16)Wc[1 * 8 + j];
            wsu[O_W0P + j * 4 + 0] = __builtin_bit_cast(uint, v);
            v[0] = (_Float16)Wc[2 * 8 + j]; v[1] = (_Float16)0.f;
            wsu[O_W0P + j * 4 + 1] = __builtin_bit_cast(uint, v);
            v[0] = (_Float16)Wc[3 * 8 + j]; v[1] = (_Float16)Wc[4 * 8 + j];
            wsu[O_W0P + j * 4 + 2] = __builtin_bit_cast(uint, v);
            v[0] = (_Float16)Wc[5 * 8 + j]; v[1] = (_Float16)0.f;
            wsu[O_W0P + j * 4 + 3] = __builtin_bit_cast(uint, v);
        }
        float bm = 0.f;
        for (int j = 0; j < 8; ++j) bm += b0[j];
        bm *= 0.125f;
        for (int j = 0; j < 8; ++j) ws[O_B0C + j] = b0[j] - bm;
    } else if (t == 2) {
        prep_hidden_layer(W1, b1, ws, wsu, O_W1P, O_B1);
    } else if (t == 3) {
        prep_hidden_layer(W2, b2, ws, wsu, O_W2P, O_B2);
    } else if (t == 4) {
        float s = 0.f;
        for (int k = 0; k < 8; ++k) s += W3[k];
        ws[O_B3] = b3[0] + s;
        for (int q = 0; q < 4; ++q) {
            h2 v;
            v[0] = (_Float16)(-2.f * W3[2 * q]);
            v[1] = (_Float16)(-2.f * W3[2 * q + 1]);
            wsu[O_W3P + q] = __builtin_bit_cast(uint, v);
        }
    }
}

__global__ __launch_bounds__(256, 8) void edge_mlp_kernel(
    const float* __restrict__ x,
    const int*   __restrict__ ei,
    const float* __restrict__ ws,
    float* __restrict__ out)
{
    const uint t = blockIdx.x * 256u + threadIdx.x;
    if (t >= N_EDGES) return;

    const uint* wsu = reinterpret_cast<const uint*>(ws);
    const uint s = (uint)ei[t];
    const uint d = (uint)ei[N_EDGES + t];

    // two random dwordx4 gathers (x[3n..3n+3], lane 3 unused)
    const f4u vsrc = *reinterpret_cast<const f4u*>(x + s * 3u);
    const f4u vdst = *reinterpret_cast<const f4u*>(x + d * 3u);

    const h2 s01 = __builtin_bit_cast(h2, __builtin_amdgcn_cvt_pkrtz(vsrc[0], vsrc[1]));
    const h2 s2z = __builtin_bit_cast(h2, __builtin_amdgcn_cvt_pkrtz(vsrc[2], 0.f));
    const h2 d01 = __builtin_bit_cast(h2, __builtin_amdgcn_cvt_pkrtz(vdst[0], vdst[1]));
    const h2 d2z = __builtin_bit_cast(h2, __builtin_amdgcn_cvt_pkrtz(vdst[2], 0.f));

    // layer 0: 4 dot2 per j with packed centered W0
    float z[HID];
#pragma unroll
    for (int j = 0; j < HID; ++j) {
        const h2 wj0 = __builtin_bit_cast(h2, wsu[O_W0P + j * 4 + 0]);
        const h2 wj1 = __builtin_bit_cast(h2, wsu[O_W0P + j * 4 + 1]);
        const h2 wj2 = __builtin_bit_cast(h2, wsu[O_W0P + j * 4 + 2]);
        const h2 wj3 = __builtin_bit_cast(h2, wsu[O_W0P + j * 4 + 3]);
        float a = FDOT2(s01, wj0, ws[O_B0C + j]);
        a = FDOT2(s2z, wj1, a);
        a = FDOT2(d01, wj2, a);
        z[j] = FDOT2(d2z, wj3, a);
    }

    h2 p[4];
    const int gco[3] = {O_GC0, O_GC1, O_GC2};
    const int bco[3] = {O_BC0, O_BC1, O_BC2};
    const int wpo[2] = {O_W1P, O_W2P};
    const int bpo[2] = {O_B1, O_B2};

#pragma unroll
    for (int L = 0; L < 3; ++L) {
        // mean-free LN + folded-tanh sigmoid (pair-rcp), pack to f16
        float va = 0.f;
#pragma unroll
        for (int j = 0; j < HID; ++j) va = __builtin_fmaf(z[j], z[j], va);
        const float r = __builtin_amdgcn_rsqf(__builtin_fmaf(va, 0.125f, LN_EPS));
        const float* gc = ws + gco[L];
        const float* bc = ws + bco[L];
        float e1[HID];
#pragma unroll
        for (int j = 0; j < HID; ++j) {
            const float y = __builtin_fmaf(z[j], r * gc[j], bc[j]);
            e1[j] = __builtin_amdgcn_exp2f(y) + 1.0f;
        }
#pragma unroll
        for (int q = 0; q < 4; ++q) {
            const float a = e1[2 * q], b = e1[2 * q + 1];
            const float pr = __builtin_amdgcn_rcpf(a * b);
            p[q] = __builtin_bit_cast(h2,
                __builtin_amdgcn_cvt_pkrtz(b * pr, a * pr));
        }
        if (L < 2) {
            const uint* wp = wsu + wpo[L];
            const float* bb = ws + bpo[L];
#pragma unroll
            for (int j = 0; j < HID; ++j) {
                float acc = FDOT2(p[0], __builtin_bit_cast(h2, wp[j * 4 + 0]), bb[j]);
                acc = FDOT2(p[1], __builtin_bit_cast(h2, wp[j * 4 + 1]), acc);
                acc = FDOT2(p[2], __builtin_bit_cast(h2, wp[j * 4 + 2]), acc);
                z[j] = FDOT2(p[3], __builtin_bit_cast(h2, wp[j * 4 + 3]), acc);
            }
        }
    }

    // final layer: out = b3' + sum u_k * (-2 W3_k)
    float acc = FDOT2(p[0], __builtin_bit_cast(h2, wsu[O_W3P + 0]), ws[O_B3]);
    acc = FDOT2(p[1], __builtin_bit_cast(h2, wsu[O_W3P + 1]), acc);
    acc = FDOT2(p[2], __builtin_bit_cast(h2, wsu[O_W3P + 2]), acc);
    out[t] = FDOT2(p[3], __builtin_bit_cast(h2, wsu[O_W3P + 3]), acc);
}

extern "C" void kernel_launch(void* const* d_in, const int* in_sizes, int n_in,
                              void* d_out, int out_size, void* d_ws, size_t ws_size,
                              hipStream_t stream) {
    const float* x   = (const float*)d_in[0];
    const int*   ei  = (const int*)d_in[1];
    const float* W0  = (const float*)d_in[2];
    const float* b0  = (const float*)d_in[3];
    const float* g0  = (const float*)d_in[4];
    const float* be0 = (const float*)d_in[5];
    const float* W1  = (const float*)d_in[6];
    const float* b1  = (const float*)d_in[7];
    const float* g1  = (const float*)d_in[8];
    const float* be1 = (const float*)d_in[9];
    const float* W2  = (const float*)d_in[10];
    const float* b2  = (const float*)d_in[11];
    const float* g2  = (const float*)d_in[12];
    const float* be2 = (const float*)d_in[13];
    const float* W3  = (const float*)d_in[14];
    const float* b3  = (const float*)d_in[15];
    float* out = (float*)d_out;
    float* ws  = (float*)d_ws;

    prep_kernel<<<1, 64, 0, stream>>>(W0, b0, g0, be0, W1, b1, g1, be1,
                                      W2, b2, g2, be2, W3, b3, ws);

    const int blocks = (N_EDGES + 255) / 256;   // 15625
    edge_mlp_kernel<<<blocks, 256, 0, stream>>>(x, ei, ws, out);
}